// Round 2
// baseline (231.931 us; speedup 1.0000x reference)
//
#include <hip/hip_runtime.h>
#include <hip/hip_cooperative_groups.h>

namespace cg = cooperative_groups;

#define B_ 8
#define CIN 64
#define COUT 64
#define H_ 128
#define W_ 128
#define HW (H_*W_)
#define OFFP 24   // shorts per pixel in St (9 taps * 2 + pad -> 48B)

typedef __attribute__((ext_vector_type(8))) short short8;   // 8 bf16 (4 VGPRs)
typedef __attribute__((ext_vector_type(4))) float f32x4;    // MFMA acc

__device__ __forceinline__ short f2bf(float f) {
    unsigned u = __float_as_uint(f);
    unsigned r = (u + 0x7fffu + ((u >> 16) & 1u)) >> 16;   // RNE
    return (short)r;
}
__device__ __forceinline__ float bf2f(short s) {
    return __uint_as_float(((unsigned)(unsigned short)s) << 16);
}

// ---------- weight prep: -> lane-linear bf16 frags ----------
template<int NT>
__device__ __forceinline__ void prep_one(const float* __restrict__ w, short* __restrict__ o,
                                         int i, int n_used) {
    int j = i & 7, lane = (i >> 3) & 63, rest = i >> 9;
    int nt = rest % NT, dc = rest / NT, c = dc & 1, d = dc >> 1;
    int oc = nt * 16 + (lane & 15);
    int ic = c * 32 + (lane >> 4) * 8 + j;
    float v = (oc < n_used) ? w[(oc * 64 + ic) * 9 + d] : 0.f;
    o[i] = f2bf(v);
}

// ---------- 3-tap prep: offsets -> 12 weights + 12 elem offsets ----------
__device__ __forceinline__ void prep3(const unsigned* __restrict__ myo, int g,
                                      int w, int h, int cko,
                                      int* __restrict__ eo, float* __restrict__ wg) {
#pragma unroll
    for (int t = 0; t < 3; ++t) {
        unsigned owk = myo[g * 3 + t];
        float ox = bf2f((short)(owk & 0xffff));
        float oy = bf2f((short)(owk >> 16));
        float xs = (float)w + ox, ys = (float)h + oy;
        float x0f = floorf(xs), y0f = floorf(ys);
        float wx1 = xs - x0f, wx0 = 1.f - wx1;
        float wy1 = ys - y0f, wy0 = 1.f - wy1;
        int x0 = (int)x0f, y0 = (int)y0f;
        int x1 = x0 + 1, y1 = y0 + 1;
        int x0c = min(max(x0, 0), W_ - 1), x1c = min(max(x1, 0), W_ - 1);
        int y0c = min(max(y0, 0), H_ - 1), y1c = min(max(y1, 0), H_ - 1);
        bool vx0 = ((unsigned)x0 < W_), vx1 = ((unsigned)x1 < W_);
        bool vy0 = ((unsigned)y0 < H_), vy1 = ((unsigned)y1 < H_);
        wg[t * 4 + 0] = (vy0 && vx0) ? wy0 * wx0 : 0.f;
        wg[t * 4 + 1] = (vy0 && vx1) ? wy0 * wx1 : 0.f;
        wg[t * 4 + 2] = (vy1 && vx0) ? wy1 * wx0 : 0.f;
        wg[t * 4 + 3] = (vy1 && vx1) ? wy1 * wx1 : 0.f;
        eo[t * 4 + 0] = ((y0c * W_ + x0c) << 6) + cko;
        eo[t * 4 + 1] = ((y0c * W_ + x1c) << 6) + cko;
        eo[t * 4 + 2] = ((y1c * W_ + x0c) << 6) + cko;
        eo[t * 4 + 3] = ((y1c * W_ + x1c) << 6) + cko;
    }
}

// ============ single cooperative kernel: tr -> conv1 -> sample -> conv2 ============
// 256 blocks x 1024 threads, exactly 1 block/CU (LDS 124.4 KB), VGPR capped at 128.
__global__ __launch_bounds__(1024, 4) void k_fused(
        const float* __restrict__ x,
        short* __restrict__ xt,
        const float* __restrict__ wof,
        const float* __restrict__ wrg,
        short* __restrict__ wt1,
        short* __restrict__ wt2,
        const float* __restrict__ bof,
        const float* __restrict__ brg,
        short* __restrict__ smp,
        float* __restrict__ out) {
    // LDS union: [0..49920) shorts = A (xt stage, 6x130x64) then S (sampled, 6x130x64)
    //            [49920..62208) shorts = St (offsets, 4x128x24)
    __shared__ short lds[62208];                       // 124,416 B
    short* S = lds;
    unsigned short* St = (unsigned short*)(lds + 49920);

    int blk = blockIdx.x;
    int tid = threadIdx.x;

    // ---------------- phase 0: weight prep + NCHW fp32 -> NHWC bf16 ----------------
    {
        int i = blk * 1024 + tid;
        if (i < 9 * 2 * 2 * 512) prep_one<2>(wof, wt1, i, 18);
        if (i < 9 * 2 * 4 * 512) prep_one<4>(wrg, wt2, i, 64);

        float* tile = (float*)lds;                     // 64*129*4 = 33,024 B overlay
        for (int q = 0; q < 4; ++q) {
            int s = blk * 4 + q;                       // 1024 (b,h) slices total
            int bb0 = s & 7, h = s >> 3;
            const float* xp = x + (size_t)bb0 * (CIN * HW) + h * W_;
            __syncthreads();                           // tile reuse guard
#pragma unroll
            for (int j = 0; j < 8; ++j) {
                int e = tid + 1024 * j;                // 8192 = 64c * 128w
                int cc = e >> 7, ww = e & 127;
                tile[cc * 129 + ww] = __builtin_nontemporal_load(xp + cc * HW + ww);
            }
            __syncthreads();
            short* op = xt + (((size_t)(bb0 << 7) + h) << 13);  // [b][h][w][c]
            int ww = tid >> 3, c0 = (tid & 7) << 3;
            short8 o;
#pragma unroll
            for (int k = 0; k < 8; ++k) o[k] = f2bf(tile[(c0 + k) * 129 + ww]);
            *(short8*)(op + ww * 64 + c0) = o;
        }
    }

    cg::this_grid().sync();    // xt + weights complete & visible device-wide

    int bb = blk & 7;
    int h0 = (blk >> 3) << 2;                          // 4 output rows h0..h0+3
    int lane = tid & 63;
    int wave = tid >> 6;                               // 0..15
    int lr = wave >> 2;                                // local output row 0..3
    int p0 = (wave & 3) * 32;                          // 32 px per wave
    int m = lane & 15, quad = lane >> 4;

    // ---------------- phase 1a: stage xt 6 rows -> LDS (XOR-swizzled) ----------------
#pragma unroll
    for (int it = 0; it < 7; ++it) {
        int s = tid + it * 1024;                       // slots: 6*130*8 = 6240
        if (s < 6240) {
            int r = s / 1040, rem = s % 1040;
            int px = rem >> 3, ck = rem & 7;
            int y = h0 - 1 + r, xx = px - 1;
            bool v = ((unsigned)y < H_) && ((unsigned)xx < W_);
            int yc = min(max(y, 0), H_ - 1), xc = min(max(xx, 0), W_ - 1);
            short8 val = *(const short8*)(xt + ((((size_t)(bb << 7) + yc) << 7) + xc) * 64 + ck * 8);
            short8 z = {0, 0, 0, 0, 0, 0, 0, 0};
            if (!v) val = z;
            *(short8*)(&S[(r * 130 + px) * 64 + ((ck ^ (px & 7)) << 3)]) = val;
        }
    }
    __syncthreads();

    // ---------------- phase 1b: conv1 (offset conv, 18 used oc) -> St (LDS) ----------------
    {
        f32x4 acc[2][2];
#pragma unroll
        for (int nt = 0; nt < 2; ++nt) {
            int oc = nt * 16 + m;
            float bv = (oc < 18) ? bof[oc] : 0.f;
#pragma unroll
            for (int mt = 0; mt < 2; ++mt) {
                acc[mt][nt][0] = bv; acc[mt][nt][1] = bv;
                acc[mt][nt][2] = bv; acc[mt][nt][3] = bv;
            }
        }
#pragma unroll
        for (int d = 0; d < 9; ++d) {
            int dy = d / 3, dx = d % 3;
#pragma unroll
            for (int c = 0; c < 2; ++c) {
                short8 a[2];
#pragma unroll
                for (int mt = 0; mt < 2; ++mt) {
                    int px = p0 + mt * 16 + m + dx;
                    a[mt] = *(const short8*)(&S[((lr + dy) * 130 + px) * 64 + (((c * 4 + quad) ^ (px & 7)) << 3)]);
                }
#pragma unroll
                for (int nt = 0; nt < 2; ++nt) {
                    short8 b = *(const short8*)(wt1 + ((((d * 2 + c) * 2 + nt) * 64 + lane) << 3));
#pragma unroll
                    for (int mt = 0; mt < 2; ++mt)
                        acc[mt][nt] = __builtin_amdgcn_mfma_f32_16x16x32_bf16(a[mt], b, acc[mt][nt], 0, 0, 0);
                }
            }
        }
        // write offsets (bf16) into St — separate LDS region, no hazard with S reads
#pragma unroll
        for (int nt = 0; nt < 2; ++nt) {
            int oc = nt * 16 + m;
            if (oc < 18) {
#pragma unroll
                for (int mt = 0; mt < 2; ++mt) {
                    int pl = lr * 128 + p0 + mt * 16 + quad * 4;
#pragma unroll
                    for (int r = 0; r < 4; ++r)
                        St[(pl + r) * OFFP + oc] = (unsigned short)f2bf(acc[mt][nt][r]);
                }
            }
        }
    }
    __syncthreads();   // St ready; A (in S region) dead beyond this point

    // ---------------- phase 1c: deformable bilinear sample (4 own rows) ----------------
    // writes sampled rows into S rows 1..4 (for own conv2) + boundary rows to smp (halo)
    {
        int ck = tid & 7, sx = tid >> 3;               // sx 0..127
        int cko = ck * 8;
        const short* xim = xt + ((size_t)bb << 20);
        for (int row = 0; row < 4; ++row) {
            int y = h0 + row;
            const unsigned* myo = (const unsigned*)(St + (row * 128 + sx) * OFFP);
            float acc[8];
#pragma unroll
            for (int i = 0; i < 8; ++i) acc[i] = 0.f;
#pragma unroll
            for (int g = 0; g < 3; ++g) {              // 3 groups of 12 gathers (VGPR cap)
                int eo[12]; float wg[12]; short8 v[12];
                prep3(myo, g, sx, y, cko, eo, wg);
#pragma unroll
                for (int n = 0; n < 12; ++n) v[n] = *(const short8*)(xim + eo[n]);
#pragma unroll
                for (int n = 0; n < 12; ++n) {
                    float wv = wg[n];
#pragma unroll
                    for (int i = 0; i < 8; ++i) acc[i] += wv * bf2f(v[n][i]);
                }
            }
            short8 o;
#pragma unroll
            for (int i = 0; i < 8; ++i) o[i] = f2bf(acc[i]);
            *(short8*)(&S[((row + 1) * 130 + (sx + 1)) * 64 + ((ck ^ ((sx + 1) & 7)) << 3)]) = o;
            if (row == 0 || row == 3)                  // only rows neighbors need as halo
                *(short8*)(smp + ((((size_t)(bb << 7) + y) << 7) + sx) * 64 + cko) = o;
        }
    }

    cg::this_grid().sync();    // halo rows in smp visible device-wide

    // ---------------- phase 2a: stage halo rows 0,5 from smp + zero pad cols ----------------
#pragma unroll
    for (int it = 0; it < 3; ++it) {
        int s = tid + it * 1024;                       // 2 rows * 130 * 8 = 2080 slots
        if (s < 2080) {
            int rr = s / 1040, rem = s % 1040;
            int px = rem >> 3, ck = rem & 7;
            int r = rr * 5;                            // LDS row 0 or 5
            int y = h0 - 1 + r, xx = px - 1;
            bool v = ((unsigned)y < H_) && ((unsigned)xx < W_);
            int yc = min(max(y, 0), H_ - 1), xc = min(max(xx, 0), W_ - 1);
            short8 val = *(const short8*)(smp + ((((size_t)(bb << 7) + yc) << 7) + xc) * 64 + ck * 8);
            short8 z = {0, 0, 0, 0, 0, 0, 0, 0};
            if (!v) val = z;
            *(short8*)(&S[(r * 130 + px) * 64 + ((ck ^ (px & 7)) << 3)]) = val;
        }
    }
    if (tid < 64) {                                    // zero cols 0,129 of rows 1..4
        int r = 1 + (tid >> 4);
        int px = ((tid >> 3) & 1) * 129;
        int ck = tid & 7;
        short8 z = {0, 0, 0, 0, 0, 0, 0, 0};
        *(short8*)(&S[(r * 130 + px) * 64 + ((ck ^ (px & 7)) << 3)]) = z;
    }
    __syncthreads();

    // ---------------- phase 2b: conv2 (64 oc) -> out ----------------
    {
        f32x4 acc[2][4];
#pragma unroll
        for (int nt = 0; nt < 4; ++nt) {
            int oc = nt * 16 + m;
            float bv = brg[oc];
#pragma unroll
            for (int mt = 0; mt < 2; ++mt) {
                acc[mt][nt][0] = bv; acc[mt][nt][1] = bv;
                acc[mt][nt][2] = bv; acc[mt][nt][3] = bv;
            }
        }
#pragma unroll
        for (int d = 0; d < 9; ++d) {
            int dy = d / 3, dx = d % 3;
#pragma unroll
            for (int c = 0; c < 2; ++c) {
                short8 a[2];
#pragma unroll
                for (int mt = 0; mt < 2; ++mt) {
                    int px = p0 + mt * 16 + m + dx;
                    a[mt] = *(const short8*)(&S[((lr + dy) * 130 + px) * 64 + (((c * 4 + quad) ^ (px & 7)) << 3)]);
                }
#pragma unroll
                for (int nt = 0; nt < 4; ++nt) {
                    short8 b = *(const short8*)(wt2 + ((((d * 2 + c) * 4 + nt) * 64 + lane) << 3));
#pragma unroll
                    for (int mt = 0; mt < 2; ++mt)
                        acc[mt][nt] = __builtin_amdgcn_mfma_f32_16x16x32_bf16(a[mt], b, acc[mt][nt], 0, 0, 0);
                }
            }
        }
#pragma unroll
        for (int nt = 0; nt < 4; ++nt) {
            int oc = nt * 16 + m;
#pragma unroll
            for (int mt = 0; mt < 2; ++mt) {
                int wpix = p0 + mt * 16 + quad * 4;
                __builtin_nontemporal_store(acc[mt][nt],
                    (f32x4*)(out + (((size_t)(bb * 64 + oc)) << 14) + ((h0 + lr) << 7) + wpix));
            }
        }
    }
}

extern "C" void kernel_launch(void* const* d_in, const int* in_sizes, int n_in,
                              void* d_out, int out_size, void* d_ws, size_t ws_size,
                              hipStream_t stream) {
    const float* x   = (const float*)d_in[0];
    const float* wof = (const float*)d_in[1];
    const float* bof = (const float*)d_in[2];
    const float* wrg = (const float*)d_in[3];
    const float* brg = (const float*)d_in[4];
    float* out = (float*)d_out;

    char* ws = (char*)d_ws;
    short* xt  = (short*)ws;                            // 16,777,216 B
    short* smp = (short*)(ws + 16777216);               // 16,777,216 B (boundary rows only used)
    short* wt1 = (short*)(ws + 2 * 16777216);           //     36,864 B
    short* wt2 = (short*)(ws + 2 * 16777216 + 36864);   //     73,728 B

    void* args[] = {(void*)&x, (void*)&xt, (void*)&wof, (void*)&wrg,
                    (void*)&wt1, (void*)&wt2, (void*)&bof, (void*)&brg,
                    (void*)&smp, (void*)&out};
    hipLaunchCooperativeKernel((const void*)k_fused, dim3(256), dim3(1024),
                               args, 0, stream);
}

// Round 3
// 147.269 us; speedup vs baseline: 1.5749x; 1.5749x over previous
//
#include <hip/hip_runtime.h>

#define B_ 8
#define CIN 64
#define COUT 64
#define H_ 128
#define W_ 128
#define HW (H_*W_)
#define OFFP 24   // shorts per pixel in St (9 taps * 2 + pad -> 48B)

typedef __attribute__((ext_vector_type(8))) short short8;   // 8 bf16 (4 VGPRs)
typedef __attribute__((ext_vector_type(4))) float f32x4;    // MFMA acc

__device__ __forceinline__ short f2bf(float f) {
    unsigned u = __float_as_uint(f);
    unsigned r = (u + 0x7fffu + ((u >> 16) & 1u)) >> 16;   // RNE
    return (short)r;
}
__device__ __forceinline__ float bf2f(short s) {
    return __uint_as_float(((unsigned)(unsigned short)s) << 16);
}

// ---------- weight prep: -> lane-linear bf16 frags ----------
template<int NT>
__device__ __forceinline__ void prep_one(const float* __restrict__ w, short* __restrict__ o,
                                         int i, int n_used) {
    int j = i & 7, lane = (i >> 3) & 63, rest = i >> 9;
    int nt = rest % NT, dc = rest / NT, c = dc & 1, d = dc >> 1;
    int oc = nt * 16 + (lane & 15);
    int ic = c * 32 + (lane >> 4) * 8 + j;
    float v = (oc < n_used) ? w[(oc * 64 + ic) * 9 + d] : 0.f;
    o[i] = f2bf(v);
}

// ---------- transpose x NCHW fp32 -> NHWC bf16, + weight prep folded in ----------
__global__ __launch_bounds__(256) void k_tr(const float* __restrict__ x,
                                            short* __restrict__ xt,
                                            const float* __restrict__ wof,
                                            const float* __restrict__ wrg,
                                            short* __restrict__ wt1,
                                            short* __restrict__ wt2) {
    int i = blockIdx.x * 256 + threadIdx.x;
    if (i < 9 * 2 * 2 * 512) prep_one<2>(wof, wt1, i, 18);
    if (i < 9 * 2 * 4 * 512) prep_one<4>(wrg, wt2, i, 64);

    __shared__ float tile[64 * 129];
    int bh = blockIdx.x;
    int bb = bh & 7, h = bh >> 3;
    const float* xp = x + (size_t)bb * (CIN * HW) + h * W_;
#pragma unroll
    for (int j = 0; j < 32; ++j) {
        int e = threadIdx.x + 256 * j;             // 8192 = 64c * 128w
        int cc = e >> 7, ww = e & 127;
        tile[cc * 129 + ww] = __builtin_nontemporal_load(xp + cc * HW + ww);
    }
    __syncthreads();
    short* op = xt + (((size_t)(bb << 7) + h) << 13);   // [b][h][w][c]
#pragma unroll
    for (int j = 0; j < 4; ++j) {
        int t = threadIdx.x + 256 * j;             // 1024 tasks: 128w x 8 chunks
        int ww = t >> 3, c0 = (t & 7) << 3;
        short8 o;
#pragma unroll
        for (int k = 0; k < 8; ++k) o[k] = f2bf(tile[(c0 + k) * 129 + ww]);
        *(short8*)(op + ww * 64 + c0) = o;         // fully coalesced 16B stores
    }
}

// ---------- 3-tap prep: offsets -> 12 weights + 12 elem offsets ----------
__device__ __forceinline__ void prep3(const unsigned* __restrict__ myo, int g,
                                      int w, int h, int cko,
                                      int* __restrict__ eo, float* __restrict__ wg) {
#pragma unroll
    for (int t = 0; t < 3; ++t) {
        unsigned owk = myo[g * 3 + t];
        float ox = bf2f((short)(owk & 0xffff));
        float oy = bf2f((short)(owk >> 16));
        float xs = (float)w + ox, ys = (float)h + oy;
        float x0f = floorf(xs), y0f = floorf(ys);
        float wx1 = xs - x0f, wx0 = 1.f - wx1;
        float wy1 = ys - y0f, wy0 = 1.f - wy1;
        int x0 = (int)x0f, y0 = (int)y0f;
        int x1 = x0 + 1, y1 = y0 + 1;
        int x0c = min(max(x0, 0), W_ - 1), x1c = min(max(x1, 0), W_ - 1);
        int y0c = min(max(y0, 0), H_ - 1), y1c = min(max(y1, 0), H_ - 1);
        bool vx0 = ((unsigned)x0 < W_), vx1 = ((unsigned)x1 < W_);
        bool vy0 = ((unsigned)y0 < H_), vy1 = ((unsigned)y1 < H_);
        wg[t * 4 + 0] = (vy0 && vx0) ? wy0 * wx0 : 0.f;
        wg[t * 4 + 1] = (vy0 && vx1) ? wy0 * wx1 : 0.f;
        wg[t * 4 + 2] = (vy1 && vx0) ? wy1 * wx0 : 0.f;
        wg[t * 4 + 3] = (vy1 && vx1) ? wy1 * wx1 : 0.f;
        eo[t * 4 + 0] = ((y0c * W_ + x0c) << 6) + cko;
        eo[t * 4 + 1] = ((y0c * W_ + x1c) << 6) + cko;
        eo[t * 4 + 2] = ((y1c * W_ + x0c) << 6) + cko;
        eo[t * 4 + 3] = ((y1c * W_ + x1c) << 6) + cko;
    }
}

// ============ conv1 (offset conv) + deformable sample, fused per block ============
// 512 thr, 2 output rows, LDS 78.8 KB -> 2 blocks/CU for inter-block overlap.
__global__ __launch_bounds__(512, 4) void k_c1s(const short* __restrict__ xt,
                                                const short* __restrict__ wt1,
                                                const float* __restrict__ bof,
                                                short* __restrict__ smp) {
    __shared__ short lds[33280 + 6144];            // A 66,560 B + St 12,288 B
    short* A = lds;
    unsigned short* St = (unsigned short*)(lds + 33280);
    int blk = blockIdx.x, tid = threadIdx.x;       // grid 512
    int bb = blk & 7;                              // image (XCD-aligned)
    int h0 = (blk >> 3) << 1;                      // 2 output rows h0, h0+1

    // stage 4 input rows h0-1 .. h0+2 (XOR-swizzled)
#pragma unroll
    for (int it = 0; it < 9; ++it) {
        int s = tid + it * 512;                    // slots: 4*130*8 = 4160
        if (s < 4160) {
            int r = s / 1040, rem = s % 1040;
            int px = rem >> 3, ck = rem & 7;
            int y = h0 - 1 + r, xx = px - 1;
            bool v = ((unsigned)y < H_) && ((unsigned)xx < W_);
            int yc = min(max(y, 0), H_ - 1), xc = min(max(xx, 0), W_ - 1);
            short8 val = *(const short8*)(xt + ((((size_t)(bb << 7) + yc) << 7) + xc) * 64 + ck * 8);
            short8 z = {0, 0, 0, 0, 0, 0, 0, 0};
            if (!v) val = z;
            *(short8*)(&A[(r * 130 + px) * 64 + ((ck ^ (px & 7)) << 3)]) = val;
        }
    }
    __syncthreads();

    int lane = tid & 63;
    int wave = tid >> 6;                           // 0..7
    int lr = wave >> 2;                            // local output row 0..1
    int p0 = (wave & 3) * 32;                      // 32 px per wave
    int m = lane & 15, quad = lane >> 4;

    // conv1 -> offsets into St (LDS only; no global round-trip)
    {
        f32x4 acc[2][2];
#pragma unroll
        for (int nt = 0; nt < 2; ++nt) {
            int oc = nt * 16 + m;
            float bv = (oc < 18) ? bof[oc] : 0.f;
#pragma unroll
            for (int mt = 0; mt < 2; ++mt) {
                acc[mt][nt][0] = bv; acc[mt][nt][1] = bv;
                acc[mt][nt][2] = bv; acc[mt][nt][3] = bv;
            }
        }
#pragma unroll
        for (int d = 0; d < 9; ++d) {
            int dy = d / 3, dx = d % 3;
#pragma unroll
            for (int c = 0; c < 2; ++c) {
                short8 a[2];
#pragma unroll
                for (int mt = 0; mt < 2; ++mt) {
                    int px = p0 + mt * 16 + m + dx;
                    a[mt] = *(const short8*)(&A[((lr + dy) * 130 + px) * 64 + (((c * 4 + quad) ^ (px & 7)) << 3)]);
                }
#pragma unroll
                for (int nt = 0; nt < 2; ++nt) {
                    short8 b = *(const short8*)(wt1 + ((((d * 2 + c) * 2 + nt) * 64 + lane) << 3));
#pragma unroll
                    for (int mt = 0; mt < 2; ++mt)
                        acc[mt][nt] = __builtin_amdgcn_mfma_f32_16x16x32_bf16(a[mt], b, acc[mt][nt], 0, 0, 0);
                }
            }
        }
#pragma unroll
        for (int nt = 0; nt < 2; ++nt) {
            int oc = nt * 16 + m;
            if (oc < 18) {
#pragma unroll
                for (int mt = 0; mt < 2; ++mt) {
                    int pl = lr * 128 + p0 + mt * 16 + quad * 4;
#pragma unroll
                    for (int r = 0; r < 4; ++r)
                        St[(pl + r) * OFFP + oc] = (unsigned short)f2bf(acc[mt][nt][r]);
                }
            }
        }
    }
    __syncthreads();   // St ready (A region dead beyond here)

    // deformable bilinear sample: 2 rows, full-width, write smp
    {
        int ck = tid & 7, sxb = tid >> 3;          // sxb 0..63
        int cko = ck * 8;
        const short* xim = xt + ((size_t)bb << 20);
#pragma unroll
        for (int row = 0; row < 2; ++row) {
            int y = h0 + row;
#pragma unroll
            for (int hf = 0; hf < 2; ++hf) {
                int sx = sxb + hf * 64;
                const unsigned* myo = (const unsigned*)(St + (row * 128 + sx) * OFFP);
                float acc[8];
#pragma unroll
                for (int i = 0; i < 8; ++i) acc[i] = 0.f;
#pragma unroll
                for (int g = 0; g < 3; ++g) {      // 3 groups of 12 gathers
                    int eo[12]; float wg[12]; short8 v[12];
                    prep3(myo, g, sx, y, cko, eo, wg);
#pragma unroll
                    for (int n = 0; n < 12; ++n) v[n] = *(const short8*)(xim + eo[n]);
#pragma unroll
                    for (int n = 0; n < 12; ++n) {
                        float wv = wg[n];
#pragma unroll
                        for (int i = 0; i < 8; ++i) acc[i] += wv * bf2f(v[n][i]);
                    }
                }
                short8 o;
#pragma unroll
                for (int i = 0; i < 8; ++i) o[i] = f2bf(acc[i]);
                *(short8*)(smp + ((((size_t)(bb << 7) + y) << 7) + sx) * 64 + cko) = o;
            }
        }
    }
}

// ============ conv2 (regular 64-oc conv): 512 thr, 2 rows, 2 blocks/CU ============
__global__ __launch_bounds__(512, 4) void k_conv2(const short* __restrict__ smp,
                                                  const short* __restrict__ wt2,
                                                  const float* __restrict__ brg,
                                                  float* __restrict__ out) {
    __shared__ short A[4 * 130 * 64];              // 66,560 B
    int blk = blockIdx.x, tid = threadIdx.x;       // grid 512
    int bb = blk & 7;
    int h0 = (blk >> 3) << 1;

#pragma unroll
    for (int it = 0; it < 9; ++it) {
        int s = tid + it * 512;                    // 4*130*8 = 4160 slots
        if (s < 4160) {
            int r = s / 1040, rem = s % 1040;
            int px = rem >> 3, ck = rem & 7;
            int y = h0 - 1 + r, xx = px - 1;
            bool v = ((unsigned)y < H_) && ((unsigned)xx < W_);
            int yc = min(max(y, 0), H_ - 1), xc = min(max(xx, 0), W_ - 1);
            short8 val = *(const short8*)(smp + ((((size_t)(bb << 7) + yc) << 7) + xc) * 64 + ck * 8);
            short8 z = {0, 0, 0, 0, 0, 0, 0, 0};
            if (!v) val = z;
            *(short8*)(&A[(r * 130 + px) * 64 + ((ck ^ (px & 7)) << 3)]) = val;
        }
    }
    __syncthreads();

    int lane = tid & 63;
    int wave = tid >> 6;                           // 0..7
    int lr = wave >> 2;                            // 0..1
    int p0 = (wave & 3) * 32;
    int m = lane & 15, quad = lane >> 4;

    f32x4 acc[2][4];
#pragma unroll
    for (int nt = 0; nt < 4; ++nt) {
        float bv = brg[nt * 16 + m];
#pragma unroll
        for (int mt = 0; mt < 2; ++mt) {
            acc[mt][nt][0] = bv; acc[mt][nt][1] = bv;
            acc[mt][nt][2] = bv; acc[mt][nt][3] = bv;
        }
    }
#pragma unroll
    for (int d = 0; d < 9; ++d) {
        int dy = d / 3, dx = d % 3;
#pragma unroll
        for (int c = 0; c < 2; ++c) {
            short8 a[2];
#pragma unroll
            for (int mt = 0; mt < 2; ++mt) {
                int px = p0 + mt * 16 + m + dx;
                a[mt] = *(const short8*)(&A[((lr + dy) * 130 + px) * 64 + (((c * 4 + quad) ^ (px & 7)) << 3)]);
            }
#pragma unroll
            for (int nt = 0; nt < 4; ++nt) {
                short8 b = *(const short8*)(wt2 + ((((d * 2 + c) * 4 + nt) * 64 + lane) << 3));
#pragma unroll
                for (int mt = 0; mt < 2; ++mt)
                    acc[mt][nt] = __builtin_amdgcn_mfma_f32_16x16x32_bf16(a[mt], b, acc[mt][nt], 0, 0, 0);
            }
        }
    }
#pragma unroll
    for (int nt = 0; nt < 4; ++nt) {
        int oc = nt * 16 + m;
#pragma unroll
        for (int mt = 0; mt < 2; ++mt) {
            int wpix = p0 + mt * 16 + quad * 4;
            __builtin_nontemporal_store(acc[mt][nt],
                (f32x4*)(out + (((size_t)(bb * 64 + oc)) << 14) + ((h0 + lr) << 7) + wpix));
        }
    }
}

extern "C" void kernel_launch(void* const* d_in, const int* in_sizes, int n_in,
                              void* d_out, int out_size, void* d_ws, size_t ws_size,
                              hipStream_t stream) {
    const float* x   = (const float*)d_in[0];
    const float* wof = (const float*)d_in[1];
    const float* bof = (const float*)d_in[2];
    const float* wrg = (const float*)d_in[3];
    const float* brg = (const float*)d_in[4];
    float* out = (float*)d_out;

    char* ws = (char*)d_ws;
    short* xt  = (short*)ws;                            // 16,777,216 B
    short* smp = (short*)(ws + 16777216);               // 16,777,216 B
    short* wt1 = (short*)(ws + 2 * 16777216);           //     36,864 B
    short* wt2 = (short*)(ws + 2 * 16777216 + 36864);   //     73,728 B

    k_tr   <<<dim3(B_ * H_),     256, 0, stream>>>(x, xt, wof, wrg, wt1, wt2);
    k_c1s  <<<dim3(B_ * H_ / 2), 512, 0, stream>>>(xt, wt1, bof, smp);
    k_conv2<<<dim3(B_ * H_ / 2), 512, 0, stream>>>(smp, wt2, brg, out);
}

// Round 5
// 143.418 us; speedup vs baseline: 1.6172x; 1.0269x over previous
//
#include <hip/hip_runtime.h>

#define B_ 8
#define CIN 64
#define COUT 64
#define H_ 128
#define W_ 128
#define HW (H_*W_)
#define OFFP 24   // shorts per pixel in St (9 taps * 2 + pad -> 48B)

typedef __attribute__((ext_vector_type(8))) short short8;   // 8 bf16 (4 VGPRs)
typedef __attribute__((ext_vector_type(4))) short s16x4;    // 4 shorts (ds_read_b64)
typedef __attribute__((ext_vector_type(4))) float f32x4;    // MFMA acc / weights

__device__ __forceinline__ short f2bf(float f) {
    unsigned u = __float_as_uint(f);
    unsigned r = (u + 0x7fffu + ((u >> 16) & 1u)) >> 16;   // RNE
    return (short)r;
}
__device__ __forceinline__ float bf2f(short s) {
    return __uint_as_float(((unsigned)(unsigned short)s) << 16);
}

// ---------- weight prep: -> lane-linear bf16 frags ----------
template<int NT>
__device__ __forceinline__ void prep_one(const float* __restrict__ w, short* __restrict__ o,
                                         int i, int n_used) {
    int j = i & 7, lane = (i >> 3) & 63, rest = i >> 9;
    int nt = rest % NT, dc = rest / NT, c = dc & 1, d = dc >> 1;
    int oc = nt * 16 + (lane & 15);
    int ic = c * 32 + (lane >> 4) * 8 + j;
    float v = (oc < n_used) ? w[(oc * 64 + ic) * 9 + d] : 0.f;
    o[i] = f2bf(v);
}

// ---------- transpose x NCHW fp32 -> NHWC bf16, + weight prep folded in ----------
__global__ __launch_bounds__(256) void k_tr(const float* __restrict__ x,
                                            short* __restrict__ xt,
                                            const float* __restrict__ wof,
                                            const float* __restrict__ wrg,
                                            short* __restrict__ wt1,
                                            short* __restrict__ wt2) {
    int i = blockIdx.x * 256 + threadIdx.x;
    if (i < 9 * 2 * 2 * 512) prep_one<2>(wof, wt1, i, 18);
    if (i < 9 * 2 * 4 * 512) prep_one<4>(wrg, wt2, i, 64);

    __shared__ float tile[64 * 129];
    int bh = blockIdx.x;
    int bb = bh & 7, h = bh >> 3;
    const float* xp = x + (size_t)bb * (CIN * HW) + h * W_;
#pragma unroll
    for (int j = 0; j < 32; ++j) {
        int e = threadIdx.x + 256 * j;             // 8192 = 64c * 128w
        int cc = e >> 7, ww = e & 127;
        tile[cc * 129 + ww] = __builtin_nontemporal_load(xp + cc * HW + ww);
    }
    __syncthreads();
    short* op = xt + (((size_t)(bb << 7) + h) << 13);   // [b][h][w][c]
#pragma unroll
    for (int j = 0; j < 4; ++j) {
        int t = threadIdx.x + 256 * j;             // 1024 tasks: 128w x 8 chunks
        int ww = t >> 3, c0 = (t & 7) << 3;
        short8 o;
#pragma unroll
        for (int k = 0; k < 8; ++k) o[k] = f2bf(tile[(c0 + k) * 129 + ww]);
        *(short8*)(op + ww * 64 + c0) = o;         // fully coalesced 16B stores
    }
}

// ---------- async staging: 4 rows h0-1..h0+2 of NHWC bf16 -> XOR-swizzled LDS ----------
// global_load_lds_dwordx4 with PRE-SWIZZLED per-lane source (linear LDS dest).
// wave w: row r = w>>1, half = w&1 (64 px). Border rows/cols -> wave-uniform zero fills.
__device__ __forceinline__ void stage4(short* A, const short* __restrict__ src,
                                       int bb, int h0, int tid) {
    int wv = tid >> 6, l = tid & 63;
    int r = wv >> 1, half = wv & 1;
    int y = h0 - 1 + r;
    int P0 = 1 + half * 64;
    int px0 = P0 + (l >> 3);                       // this lane's pixel slot
    int ckl = l & 7;                               // linear LDS chunk slot
    if ((unsigned)y < H_) {
        int ckg = ckl ^ (px0 & 7);                 // pre-swizzled source chunk
        const short* gp = src + ((((size_t)(bb << 7) + y) << 7) + (px0 - 1)) * 64 + ckg * 8;
#pragma unroll
        for (int i = 0; i < 8; ++i) {
            short* lp = &A[(r * 130 + P0 + i * 8) * 64];   // wave-uniform base
            __builtin_amdgcn_global_load_lds(
                (const __attribute__((address_space(1))) void*)(gp + i * 512),
                (__attribute__((address_space(3))) void*)lp, 16, 0, 0);
        }
    } else {                                       // out-of-range row -> zeros
        short8 z = {0, 0, 0, 0, 0, 0, 0, 0};
#pragma unroll
        for (int i = 0; i < 8; ++i)
            *(short8*)(&A[(r * 130 + P0 + i * 8) * 64 + l * 8]) = z;
    }
    if (tid < 64) {                                // zero pad cols 0,129 for all 4 rows
        int rr = tid >> 4, side = (tid >> 3) & 1, ck = tid & 7;
        int px = side * 129;
        short8 z = {0, 0, 0, 0, 0, 0, 0, 0};
        *(short8*)(&A[(rr * 130 + px) * 64 + ((ck ^ (px & 7)) << 3)]) = z;
    }
}

// ---------- per-(pixel,tap) prep: offsets -> 4 clamped indices + 4 weights ----------
__device__ __forceinline__ void prep_task(int t, int h0,
                                          const unsigned short* __restrict__ St,
                                          s16x4* __restrict__ idxs,
                                          f32x4* __restrict__ wgs) {
    int pxl = (int)((unsigned)t / 9u);
    int tap = t - pxl * 9;
    int row = pxl >> 7, sx = pxl & 127;
    unsigned owk = *(const unsigned*)(St + pxl * OFFP + tap * 2);
    float ox = bf2f((short)(owk & 0xffff));
    float oy = bf2f((short)(owk >> 16));
    float xs = (float)sx + ox, ys = (float)(h0 + row) + oy;
    float x0f = floorf(xs), y0f = floorf(ys);
    float wx1 = xs - x0f, wx0 = 1.f - wx1;
    float wy1 = ys - y0f, wy0 = 1.f - wy1;
    int x0 = (int)x0f, y0 = (int)y0f;
    int x1 = x0 + 1, y1 = y0 + 1;
    int x0c = min(max(x0, 0), W_ - 1), x1c = min(max(x1, 0), W_ - 1);
    int y0c = min(max(y0, 0), H_ - 1), y1c = min(max(y1, 0), H_ - 1);
    bool vx0 = ((unsigned)x0 < W_), vx1 = ((unsigned)x1 < W_);
    bool vy0 = ((unsigned)y0 < H_), vy1 = ((unsigned)y1 < H_);
    f32x4 wg;
    wg[0] = (vy0 && vx0) ? wy0 * wx0 : 0.f;
    wg[1] = (vy0 && vx1) ? wy0 * wx1 : 0.f;
    wg[2] = (vy1 && vx0) ? wy1 * wx0 : 0.f;
    wg[3] = (vy1 && vx1) ? wy1 * wx1 : 0.f;
    s16x4 id;
    id[0] = (short)(y0c * W_ + x0c);
    id[1] = (short)(y0c * W_ + x1c);
    id[2] = (short)(y1c * W_ + x0c);
    id[3] = (short)(y1c * W_ + x1c);
    idxs[t] = id;
    wgs[t] = wg;
}

// ============ conv1 (offset conv) + deformable sample, fused per block ============
// 512 thr, 2 output rows, LDS 78.8 KB -> 2 blocks/CU.
__global__ __launch_bounds__(512, 4) void k_c1s(const short* __restrict__ xt,
                                                const short* __restrict__ wt1,
                                                const float* __restrict__ bof,
                                                short* __restrict__ smp) {
    __shared__ __align__(16) short lds[33280 + 6144];  // A/prep 66,560 B + St 12,288 B
    short* A = lds;
    unsigned short* St = (unsigned short*)(lds + 33280);
    int blk = blockIdx.x, tid = threadIdx.x;       // grid 512
    int bb = blk & 7;                              // image (XCD-aligned for L2 locality)
    int h0 = (blk >> 3) << 1;                      // 2 output rows h0, h0+1

    stage4(A, xt, bb, h0, tid);                    // async global->LDS (swizzled)
    __syncthreads();

    int lane = tid & 63;
    int wave = tid >> 6;                           // 0..7
    int lr = wave >> 2;                            // local output row 0..1
    int p0 = (wave & 3) * 32;                      // 32 px per wave
    int m = lane & 15, quad = lane >> 4;

    // conv1 -> offsets into St (LDS only)
    {
        f32x4 acc[2][2];
#pragma unroll
        for (int nt = 0; nt < 2; ++nt) {
            int oc = nt * 16 + m;
            float bv = (oc < 18) ? bof[oc] : 0.f;
#pragma unroll
            for (int mt = 0; mt < 2; ++mt) {
                acc[mt][nt][0] = bv; acc[mt][nt][1] = bv;
                acc[mt][nt][2] = bv; acc[mt][nt][3] = bv;
            }
        }
#pragma unroll
        for (int d = 0; d < 9; ++d) {
            int dy = d / 3, dx = d % 3;
#pragma unroll
            for (int c = 0; c < 2; ++c) {
                short8 a[2];
#pragma unroll
                for (int mt = 0; mt < 2; ++mt) {
                    int px = p0 + mt * 16 + m + dx;
                    a[mt] = *(const short8*)(&A[((lr + dy) * 130 + px) * 64 + (((c * 4 + quad) ^ (px & 7)) << 3)]);
                }
#pragma unroll
                for (int nt = 0; nt < 2; ++nt) {
                    short8 b = *(const short8*)(wt1 + ((((d * 2 + c) * 2 + nt) * 64 + lane) << 3));
#pragma unroll
                    for (int mt = 0; mt < 2; ++mt)
                        acc[mt][nt] = __builtin_amdgcn_mfma_f32_16x16x32_bf16(a[mt], b, acc[mt][nt], 0, 0, 0);
                }
            }
        }
#pragma unroll
        for (int nt = 0; nt < 2; ++nt) {
            int oc = nt * 16 + m;
            if (oc < 18) {
#pragma unroll
                for (int mt = 0; mt < 2; ++mt) {
                    int pl = lr * 128 + p0 + mt * 16 + quad * 4;
#pragma unroll
                    for (int r = 0; r < 4; ++r)
                        St[(pl + r) * OFFP + oc] = (unsigned short)f2bf(acc[mt][nt][r]);
                }
            }
        }
    }
    __syncthreads();   // St ready; A (staged input) dead beyond here

    // shared prep into dead A region: 2304 tasks = 256 px * 9 taps, each ONCE
    s16x4* idxs = (s16x4*)lds;                     // 2304 * 8 B  = 18,432 B
    f32x4*  wgs  = (f32x4*)(lds + 9216);           // 2304 * 16 B = 36,864 B (tot 55.3 KB)
    {
#pragma unroll
        for (int k = 0; k < 4; ++k) prep_task(tid + 512 * k, h0, St, idxs, wgs);
        if (tid < 256) prep_task(2048 + tid, h0, St, idxs, wgs);
    }
    __syncthreads();

    // deformable bilinear sample: broadcast ds_reads of prep, 12-deep gather MLP
    {
        int ck = tid & 7, sxb = tid >> 3;          // sxb 0..63
        int cko = ck * 8;
        const short* xim = xt + ((size_t)bb << 20);
#pragma unroll
        for (int row = 0; row < 2; ++row) {
            int y = h0 + row;
#pragma unroll
            for (int hf = 0; hf < 2; ++hf) {
                int sx = sxb + hf * 64;
                int pb = (row * 128 + sx) * 9;
                float acc[8];
#pragma unroll
                for (int i = 0; i < 8; ++i) acc[i] = 0.f;
#pragma unroll
                for (int g = 0; g < 3; ++g) {      // taps 3g..3g+2
                    int eo[12]; float wf[12]; short8 v[12];
#pragma unroll
                    for (int t2 = 0; t2 < 3; ++t2) {
                        s16x4 id = idxs[pb + g * 3 + t2];
                        f32x4 wv = wgs[pb + g * 3 + t2];
#pragma unroll
                        for (int c = 0; c < 4; ++c) {
                            eo[t2 * 4 + c] = (((int)id[c]) << 6) + cko;
                            wf[t2 * 4 + c] = wv[c];
                        }
                    }
#pragma unroll
                    for (int n = 0; n < 12; ++n) v[n] = *(const short8*)(xim + eo[n]);
#pragma unroll
                    for (int n = 0; n < 12; ++n) {
                        float wvv = wf[n];
#pragma unroll
                        for (int i = 0; i < 8; ++i) acc[i] += wvv * bf2f(v[n][i]);
                    }
                }
                short8 o;
#pragma unroll
                for (int i = 0; i < 8; ++i) o[i] = f2bf(acc[i]);
                *(short8*)(smp + ((((size_t)(bb << 7) + y) << 7) + sx) * 64 + cko) = o;
            }
        }
    }
}

// ============ conv2 (regular 64-oc conv): 512 thr, 2 rows, 2 blocks/CU ============
__global__ __launch_bounds__(512, 4) void k_conv2(const short* __restrict__ smp,
                                                  const short* __restrict__ wt2,
                                                  const float* __restrict__ brg,
                                                  float* __restrict__ out) {
    __shared__ __align__(16) short A[4 * 130 * 64];    // 66,560 B
    int blk = blockIdx.x, tid = threadIdx.x;       // grid 512
    int bb = blk & 7;
    int h0 = (blk >> 3) << 1;

    stage4(A, smp, bb, h0, tid);                   // async global->LDS (swizzled)
    __syncthreads();

    int lane = tid & 63;
    int wave = tid >> 6;                           // 0..7
    int lr = wave >> 2;                            // 0..1
    int p0 = (wave & 3) * 32;
    int m = lane & 15, quad = lane >> 4;

    f32x4 acc[2][4];
#pragma unroll
    for (int nt = 0; nt < 4; ++nt) {
        float bv = brg[nt * 16 + m];
#pragma unroll
        for (int mt = 0; mt < 2; ++mt) {
            acc[mt][nt][0] = bv; acc[mt][nt][1] = bv;
            acc[mt][nt][2] = bv; acc[mt][nt][3] = bv;
        }
    }
#pragma unroll
    for (int d = 0; d < 9; ++d) {
        int dy = d / 3, dx = d % 3;
#pragma unroll
        for (int c = 0; c < 2; ++c) {
            short8 a[2];
#pragma unroll
            for (int mt = 0; mt < 2; ++mt) {
                int px = p0 + mt * 16 + m + dx;
                a[mt] = *(const short8*)(&A[((lr + dy) * 130 + px) * 64 + (((c * 4 + quad) ^ (px & 7)) << 3)]);
            }
#pragma unroll
            for (int nt = 0; nt < 4; ++nt) {
                short8 b = *(const short8*)(wt2 + ((((d * 2 + c) * 4 + nt) * 64 + lane) << 3));
#pragma unroll
                for (int mt = 0; mt < 2; ++mt)
                    acc[mt][nt] = __builtin_amdgcn_mfma_f32_16x16x32_bf16(a[mt], b, acc[mt][nt], 0, 0, 0);
            }
        }
    }
#pragma unroll
    for (int nt = 0; nt < 4; ++nt) {
        int oc = nt * 16 + m;
#pragma unroll
        for (int mt = 0; mt < 2; ++mt) {
            int wpix = p0 + mt * 16 + quad * 4;
            __builtin_nontemporal_store(acc[mt][nt],
                (f32x4*)(out + (((size_t)(bb * 64 + oc)) << 14) + ((h0 + lr) << 7) + wpix));
        }
    }
}

extern "C" void kernel_launch(void* const* d_in, const int* in_sizes, int n_in,
                              void* d_out, int out_size, void* d_ws, size_t ws_size,
                              hipStream_t stream) {
    const float* x   = (const float*)d_in[0];
    const float* wof = (const float*)d_in[1];
    const float* bof = (const float*)d_in[2];
    const float* wrg = (const float*)d_in[3];
    const float* brg = (const float*)d_in[4];
    float* out = (float*)d_out;

    char* ws = (char*)d_ws;
    short* xt  = (short*)ws;                            // 16,777,216 B
    short* smp = (short*)(ws + 16777216);               // 16,777,216 B
    short* wt1 = (short*)(ws + 2 * 16777216);           //     36,864 B
    short* wt2 = (short*)(ws + 2 * 16777216 + 36864);   //     73,728 B

    k_tr   <<<dim3(B_ * H_),     256, 0, stream>>>(x, xt, wof, wrg, wt1, wt2);
    k_c1s  <<<dim3(B_ * H_ / 2), 512, 0, stream>>>(xt, wt1, bof, smp);
    k_conv2<<<dim3(B_ * H_ / 2), 512, 0, stream>>>(smp, wt2, brg, out);
}